// Round 1
// baseline (1927.226 us; speedup 1.0000x reference)
//
#include <hip/hip_runtime.h>

#define BB 128
#define TT 2048
#define II 64
#define HH 128
#define GG 512  // 4*H

typedef _Float16 h2 __attribute__((ext_vector_type(2)));

__device__ __forceinline__ h2 mkh2(float a, float b) {
    h2 r; r.x = (_Float16)a; r.y = (_Float16)b; return r;
}

__device__ __forceinline__ h2 u2h(unsigned u) {
    return __builtin_bit_cast(h2, u);
}

__device__ __forceinline__ float fdot2f(h2 a, h2 b, float c) {
#if __has_builtin(__builtin_amdgcn_fdot2)
    return __builtin_amdgcn_fdot2(a, b, c, false);
#else
    return fmaf((float)a.y, (float)b.y, fmaf((float)a.x, (float)b.x, c));
#endif
}

__device__ __forceinline__ float rcp_fast(float x) {
    return __builtin_amdgcn_rcpf(x);
}

__device__ __forceinline__ float tanh_fast(float x) {
    // tanh(x) = 2/(1+e^-2x) - 1
    return fmaf(rcp_fast(1.0f + __expf(-2.0f * x)), 2.0f, -1.0f);
}

// DPP quad_perm cross-lane (within groups of 4 lanes), pure VALU — no LDS.
template <int CTRL>
__device__ __forceinline__ float dppq(float x) {
#if __has_builtin(__builtin_amdgcn_update_dpp)
    int i = __builtin_bit_cast(int, x);
    int r = __builtin_amdgcn_update_dpp(i, i, CTRL, 0xF, 0xF, true);
    return __builtin_bit_cast(float, r);
#else
    return __shfl_xor(x, (CTRL == 177) ? 1 : (CTRL == 78) ? 2 : 3, 4);
#endif
}

// Workgroup barrier that only waits on LDS ops (lgkmcnt), NOT on outstanding
// global loads/stores. __syncthreads() emits s_waitcnt vmcnt(0) lgkmcnt(0)
// before s_barrier, which puts the out_e global-store completion AND the
// x-prefetch load completion on the per-step critical path (2048 times).
// Cross-wave correctness here only needs LDS visibility.
__device__ __forceinline__ void barrier_lds_only() {
    asm volatile("s_waitcnt lgkmcnt(0)" ::: "memory");
    __builtin_amdgcn_s_barrier();
    asm volatile("" ::: "memory");
}

// One workgroup per batch element; 512 threads.
// lane = 4k+gt: the 4 gates (i,f,g,o) of h-element j = wave*16+k live in one
// quad. Gate exchange via DPP quad_perm; c held redundantly in each quad lane.
// Single (LDS-only) barrier per step; s_x/s_h double-buffered.
__global__ __launch_bounds__(512, 2) void lstm_fused_kernel(
    const float* __restrict__ input,  // [B,T,I]
    const float* __restrict__ h0,     // [B,H]
    const float* __restrict__ c0,     // [B,H]
    const float* __restrict__ W_ih,   // [4H,I]
    const float* __restrict__ W_hh,   // [4H,H]
    const float* __restrict__ b_ih,   // [4H]
    const float* __restrict__ b_hh,   // [4H]
    float* __restrict__ out)          // [B*H] h_last, then [B,T,H] encoded
{
    __shared__ __align__(16) h2 s_x[2][II / 2];   // double-buffered x_t (fp16)
    __shared__ __align__(16) h2 s_h[2][HH / 2];   // double-buffered h   (fp16)

    const int tid  = threadIdx.x;
    const int b    = blockIdx.x;
    const int lane = tid & 63;
    const int w    = tid >> 6;
    const int gt   = lane & 3;                  // 0=i 1=f 2=g 3=o
    const int j    = (w << 4) | (lane >> 2);    // h element [0,128)
    const int row  = (gt << 7) | j;             // weight row gt*128+j

    // ---- weight rows into registers, fp32 -> fp16x2 ----
    h2 wih[II / 2];   // 32 regs
    h2 whh[HH / 2];   // 64 regs
    {
        const float4* p = reinterpret_cast<const float4*>(W_ih + row * II);
#pragma unroll
        for (int q = 0; q < II / 4; ++q) {
            float4 v = p[q];
            wih[2 * q]     = mkh2(v.x, v.y);
            wih[2 * q + 1] = mkh2(v.z, v.w);
        }
    }
    {
        const float4* p = reinterpret_cast<const float4*>(W_hh + row * HH);
#pragma unroll
        for (int q = 0; q < HH / 4; ++q) {
            float4 v = p[q];
            whh[2 * q]     = mkh2(v.x, v.y);
            whh[2 * q + 1] = mkh2(v.z, v.w);
        }
    }
    const float bias = b_ih[row] + b_hh[row];

    // ---- state init ----
    float c = c0[(size_t)b * HH + j];            // redundant per quad
    if (tid < 64) {
        float2 hv = reinterpret_cast<const float2*>(h0 + (size_t)b * HH)[tid];
        s_h[0][tid] = mkh2(hv.x, hv.y);
    }

    // ---- x prefetch: threads 0..31 hold 4 future float2 of x ----
    const float2* xin = reinterpret_cast<const float2*>(input) + (size_t)b * TT * 32 + tid;
    float2 xb0, xb1, xb2, xb3;
    if (tid < 32) {
        xb0 = xin[(size_t)0 * 32];
        xb1 = xin[(size_t)1 * 32];
        xb2 = xin[(size_t)2 * 32];
        xb3 = xin[(size_t)3 * 32];
        s_x[0][tid] = mkh2(xb0.x, xb0.y);   // stage step 0
        xb0 = xin[(size_t)4 * 32];          // xb0 now holds x_4
    }
    barrier_lds_only();

    float* out_h = out;            // [B*H]
    float* out_e = out + BB * HH;  // [B*T*H]
    float hlast = 0.0f;

    // step t: read s_x/s_h[t&1]; xbn holds x_{t+1}, staged into buf (t+1)&1,
    // then refetched to x_{t+5}.
    auto step = [&](int t, float2& xbn) {
        const int cb = t & 1, nb = cb ^ 1;

        if (tid < 32) {
            s_x[nb][tid] = mkh2(xbn.x, xbn.y);
            int tn = t + 5; if (tn > TT - 1) tn = TT - 1;   // clamped, harmless
            xbn = xin[(size_t)tn * 32];
        }

        const uint4* sx4 = reinterpret_cast<const uint4*>(s_x[cb]);  // 8
        const uint4* sh4 = reinterpret_cast<const uint4*>(s_h[cb]);  // 16

        // 8 independent accumulator chains (depth 12) instead of 4 (depth 24)
        // to shorten the post-LDS dependency tail.
        float acc[8];
        acc[0] = bias;
#pragma unroll
        for (int k = 1; k < 8; ++k) acc[k] = 0.0f;
#pragma unroll
        for (int q = 0; q < 8; ++q) {
            uint4 v = sx4[q];
            const int o = (q & 1) << 2;
            acc[o + 0] = fdot2f(wih[4 * q + 0], u2h(v.x), acc[o + 0]);
            acc[o + 1] = fdot2f(wih[4 * q + 1], u2h(v.y), acc[o + 1]);
            acc[o + 2] = fdot2f(wih[4 * q + 2], u2h(v.z), acc[o + 2]);
            acc[o + 3] = fdot2f(wih[4 * q + 3], u2h(v.w), acc[o + 3]);
        }
#pragma unroll
        for (int q = 0; q < 16; ++q) {
            uint4 v = sh4[q];
            const int o = (q & 1) << 2;
            acc[o + 0] = fdot2f(whh[4 * q + 0], u2h(v.x), acc[o + 0]);
            acc[o + 1] = fdot2f(whh[4 * q + 1], u2h(v.y), acc[o + 1]);
            acc[o + 2] = fdot2f(whh[4 * q + 2], u2h(v.z), acc[o + 2]);
            acc[o + 3] = fdot2f(whh[4 * q + 3], u2h(v.w), acc[o + 3]);
        }
        float gate = ((acc[0] + acc[4]) + (acc[1] + acc[5])) +
                     ((acc[2] + acc[6]) + (acc[3] + acc[7]));

        // activation for own gate type (predicated, no divergence):
        // gt==2 -> tanh, else sigmoid
        float pre = (gt == 2) ? 2.0f * gate : gate;
        float sg  = rcp_fast(1.0f + __expf(-pre));
        float act = (gt == 2) ? fmaf(sg, 2.0f, -1.0f) : sg;

        // quad butterfly: v1 = lane^1, v2 = lane^2, v3 = lane^3
        float v0 = act;
        float v1 = dppq<177>(act);   // quad_perm [1,0,3,2]
        float v2 = dppq<78>(act);    // quad_perm [2,3,0,1]
        float v3 = dppq<27>(act);    // quad_perm [3,2,1,0]
        // v_k holds gate gt^k; select gate 0..3
        float sA = (gt & 1) ? v1 : v0;
        float sB = (gt & 1) ? v3 : v2;
        float sC = (gt & 1) ? v0 : v1;
        float sD = (gt & 1) ? v2 : v3;
        float iv = (gt & 2) ? sB : sA;
        float gv = (gt & 2) ? sA : sB;
        float fv = (gt & 2) ? sD : sC;
        float ov = (gt & 2) ? sC : sD;

        c = fmaf(fv, c, iv * gv);
        float hv = ov * tanh_fast(c);
        hlast = hv;

        if (gt == 0) reinterpret_cast<_Float16*>(s_h[nb])[j] = (_Float16)hv;
        if (gt == 1) out_e[((size_t)b * TT + t) * HH + j] = hv;

        barrier_lds_only();
    };

    for (int t0 = 0; t0 < TT; t0 += 4) {
        step(t0 + 0, xb1);
        step(t0 + 1, xb2);
        step(t0 + 2, xb3);
        step(t0 + 3, xb0);
    }

    if (gt == 2) out_h[(size_t)b * HH + j] = hlast;
}

extern "C" void kernel_launch(void* const* d_in, const int* in_sizes, int n_in,
                              void* d_out, int out_size, void* d_ws, size_t ws_size,
                              hipStream_t stream) {
    const float* input = (const float*)d_in[0];
    const float* h0    = (const float*)d_in[1];
    const float* c0    = (const float*)d_in[2];
    const float* W_ih  = (const float*)d_in[3];
    const float* W_hh  = (const float*)d_in[4];
    const float* b_ih  = (const float*)d_in[5];
    const float* b_hh  = (const float*)d_in[6];
    float* out = (float*)d_out;

    hipLaunchKernelGGL(lstm_fused_kernel, dim3(BB), dim3(GG), 0, stream,
                       input, h0, c0, W_ih, W_hh, b_ih, b_hh, out);
}

// Round 2
// 1572.118 us; speedup vs baseline: 1.2259x; 1.2259x over previous
//
#include <hip/hip_runtime.h>

#define BB 128
#define TT 2048
#define II 64
#define HH 128
#define GG 512  // 4*H
#define KK 192  // I + H (concatenated dot length)
#define KC 48   // K-chunk per lane (KK/4)

typedef _Float16 h2 __attribute__((ext_vector_type(2)));

__device__ __forceinline__ h2 mkh2(float a, float b) {
    h2 r; r.x = (_Float16)a; r.y = (_Float16)b; return r;
}

__device__ __forceinline__ h2 u2h(unsigned u) {
    return __builtin_bit_cast(h2, u);
}

__device__ __forceinline__ float fdot2f(h2 a, h2 b, float c) {
#if __has_builtin(__builtin_amdgcn_fdot2)
    return __builtin_amdgcn_fdot2(a, b, c, false);
#else
    return fmaf((float)a.y, (float)b.y, fmaf((float)a.x, (float)b.x, c));
#endif
}

__device__ __forceinline__ float rcp_fast(float x) {
    return __builtin_amdgcn_rcpf(x);
}

__device__ __forceinline__ float tanh_fast(float x) {
    // tanh(x) = 2/(1+e^-2x) - 1
    return fmaf(rcp_fast(1.0f + __expf(-2.0f * x)), 2.0f, -1.0f);
}

__device__ __forceinline__ float sigmoid_fast(float x) {
    return rcp_fast(1.0f + __expf(-x));
}

// DPP quad_perm cross-lane (within groups of 4 lanes), pure VALU — no LDS.
template <int CTRL>
__device__ __forceinline__ float dppq(float x) {
#if __has_builtin(__builtin_amdgcn_update_dpp)
    int i = __builtin_bit_cast(int, x);
    int r = __builtin_amdgcn_update_dpp(i, i, CTRL, 0xF, 0xF, true);
    return __builtin_bit_cast(float, r);
#else
    return __shfl_xor(x, (CTRL == 177) ? 1 : (CTRL == 78) ? 2 : 3, 4);
#endif
}

// One workgroup per batch element; 512 threads.
// Quad (lanes 4q..4q+3) owns h-element j = wave*16+q. Lane kc = lane&3
// computes PARTIAL dots of ALL FOUR gate rows (g*128+j) over K-chunk
// [48*kc, 48*kc+48) of the concatenated [x | h] vector. A 2-round DPP quad
// butterfly then gives every lane all four full gate pre-activations, so no
// post-activation gate exchange is needed. LDS traffic per thread per step:
// 96 B (6 x ds_read_b128) vs 384 B in the row-per-thread layout.
__global__ __launch_bounds__(512, 2) void lstm_fused_kernel(
    const float* __restrict__ input,  // [B,T,I]
    const float* __restrict__ h0,     // [B,H]
    const float* __restrict__ c0,     // [B,H]
    const float* __restrict__ W_ih,   // [4H,I]
    const float* __restrict__ W_hh,   // [4H,H]
    const float* __restrict__ b_ih,   // [4H]
    const float* __restrict__ b_hh,   // [4H]
    float* __restrict__ out)          // [B*H] h_last, then [B,T,H] encoded
{
    // Concatenated [x | h] step vector, double-buffered, fp16:
    // h2 idx [0,32) = x_t (64 halfs), [32,96) = h (128 halfs).
    __shared__ __align__(16) h2 s_xh[2][KK / 2];

    const int tid  = threadIdx.x;
    const int b    = blockIdx.x;
    const int lane = tid & 63;
    const int w    = tid >> 6;
    const int kc   = lane & 3;                  // K-chunk 0..3
    const int j    = (w << 4) | (lane >> 2);    // h element [0,128)

    // ---- weight chunks into registers, fp32 -> fp16x2 ----
    // wreg[g][m]: halfs [2m, 2m+1] of chunk kc of row g*128+j of [W_ih|W_hh].
    h2 wreg[4][KC / 2];   // 96 h2 regs (same budget as row-per-thread)
    float bias[4];
#pragma unroll
    for (int g = 0; g < 4; ++g) {
        const int row = (g << 7) | j;
        bias[g] = b_ih[row] + b_hh[row];
        const float2* wi = reinterpret_cast<const float2*>(W_ih + row * II);
        const float2* wh = reinterpret_cast<const float2*>(W_hh + row * HH);
#pragma unroll
        for (int m = 0; m < KC / 2; ++m) {
            const int k = KC * kc + 2 * m;      // even; never straddles II
            float2 v = (k < II) ? wi[k >> 1] : wh[(k - II) >> 1];
            wreg[g][m] = mkh2(v.x, v.y);
        }
    }

    // ---- state init ----
    float c = c0[(size_t)b * HH + j];            // redundant per quad
    if (tid < 64) {
        float2 hv = reinterpret_cast<const float2*>(h0 + (size_t)b * HH)[tid];
        s_xh[0][32 + tid] = mkh2(hv.x, hv.y);
    }

    // ---- x prefetch: threads 0..31 hold 4 future float2 of x ----
    const float2* xin = reinterpret_cast<const float2*>(input) + (size_t)b * TT * 32 + tid;
    float2 xb0, xb1, xb2, xb3;
    if (tid < 32) {
        xb0 = xin[(size_t)0 * 32];
        xb1 = xin[(size_t)1 * 32];
        xb2 = xin[(size_t)2 * 32];
        xb3 = xin[(size_t)3 * 32];
        s_xh[0][tid] = mkh2(xb0.x, xb0.y);   // stage x for step 0
        xb0 = xin[(size_t)4 * 32];           // xb0 now holds x_4
    }
    __syncthreads();

    float* out_h = out;            // [B*H]
    float* out_e = out + BB * HH;  // [B*T*H]
    float hlast = 0.0f;

    // step t: read s_xh[t&1]; xbn holds x_{t+1}, staged into buf (t+1)&1,
    // then refetched to x_{t+5}.
    auto step = [&](int t, float2& xbn) {
        const int cb = t & 1, nb = cb ^ 1;

        if (tid < 32) {
            s_xh[nb][tid] = mkh2(xbn.x, xbn.y);
            int tn = t + 5; if (tn > TT - 1) tn = TT - 1;   // clamped, harmless
            xbn = xin[(size_t)tn * 32];
        }

        // This lane's 96-byte K-chunk: 6 x uint4 (24 h2).
        const uint4* basep = reinterpret_cast<const uint4*>(
            reinterpret_cast<const char*>(s_xh[cb]) + kc * (KC * 2));

        float p0 = 0.0f, p1 = 0.0f, p2 = 0.0f, p3 = 0.0f;
#pragma unroll
        for (int q = 0; q < 6; ++q) {
            uint4 v = basep[q];
            p0 = fdot2f(wreg[0][4 * q + 0], u2h(v.x), p0);
            p1 = fdot2f(wreg[1][4 * q + 0], u2h(v.x), p1);
            p2 = fdot2f(wreg[2][4 * q + 0], u2h(v.x), p2);
            p3 = fdot2f(wreg[3][4 * q + 0], u2h(v.x), p3);
            p0 = fdot2f(wreg[0][4 * q + 1], u2h(v.y), p0);
            p1 = fdot2f(wreg[1][4 * q + 1], u2h(v.y), p1);
            p2 = fdot2f(wreg[2][4 * q + 1], u2h(v.y), p2);
            p3 = fdot2f(wreg[3][4 * q + 1], u2h(v.y), p3);
            p0 = fdot2f(wreg[0][4 * q + 2], u2h(v.z), p0);
            p1 = fdot2f(wreg[1][4 * q + 2], u2h(v.z), p1);
            p2 = fdot2f(wreg[2][4 * q + 2], u2h(v.z), p2);
            p3 = fdot2f(wreg[3][4 * q + 2], u2h(v.z), p3);
            p0 = fdot2f(wreg[0][4 * q + 3], u2h(v.w), p0);
            p1 = fdot2f(wreg[1][4 * q + 3], u2h(v.w), p1);
            p2 = fdot2f(wreg[2][4 * q + 3], u2h(v.w), p2);
            p3 = fdot2f(wreg[3][4 * q + 3], u2h(v.w), p3);
        }

        // 2-round quad butterfly: every lane gets all four full gate sums.
        float u0 = p0 + dppq<177>(p0);   // + lane^1
        float u1 = p1 + dppq<177>(p1);
        float u2 = p2 + dppq<177>(p2);
        float u3 = p3 + dppq<177>(p3);
        u0 += dppq<78>(u0);              // + lane^2
        u1 += dppq<78>(u1);
        u2 += dppq<78>(u2);
        u3 += dppq<78>(u3);

        // all lanes compute all four activations (ILP, no exchange chain)
        float ig = sigmoid_fast(u0 + bias[0]);
        float fg = sigmoid_fast(u1 + bias[1]);
        float gg = tanh_fast(u2 + bias[2]);
        float og = sigmoid_fast(u3 + bias[3]);

        c = fmaf(fg, c, ig * gg);
        float hv = og * tanh_fast(c);
        hlast = hv;

        if (kc == 0) reinterpret_cast<_Float16*>(s_xh[nb])[II + j] = (_Float16)hv;
        if (kc == 1) out_e[((size_t)b * TT + t) * HH + j] = hv;

        __syncthreads();
    };

    for (int t0 = 0; t0 < TT; t0 += 4) {
        step(t0 + 0, xb1);
        step(t0 + 1, xb2);
        step(t0 + 2, xb3);
        step(t0 + 3, xb0);
    }

    if (kc == 2) out_h[(size_t)b * HH + j] = hlast;
}

extern "C" void kernel_launch(void* const* d_in, const int* in_sizes, int n_in,
                              void* d_out, int out_size, void* d_ws, size_t ws_size,
                              hipStream_t stream) {
    const float* input = (const float*)d_in[0];
    const float* h0    = (const float*)d_in[1];
    const float* c0    = (const float*)d_in[2];
    const float* W_ih  = (const float*)d_in[3];
    const float* W_hh  = (const float*)d_in[4];
    const float* b_ih  = (const float*)d_in[5];
    const float* b_hh  = (const float*)d_in[6];
    float* out = (float*)d_out;

    hipLaunchKernelGGL(lstm_fused_kernel, dim3(BB), dim3(GG), 0, stream,
                       input, h0, c0, W_ih, W_hh, b_ih, b_hh, out);
}